// Round 1
// baseline (412.807 us; speedup 1.0000x reference)
//
#include <hip/hip_runtime.h>

// out[b] = W[b] - (W[b]@x[b] + eta*gL[b]) * x[b]^T
// B=64, D=1024, fp32. Memory-bound: 256 MiB read (W) + 256 MiB write (out).
// One 256-thread block per row of W (65536 blocks). Each thread owns 4
// consecutive columns (float4): the same x[j] values serve both the dot
// product and the rank-1 update, so W is read exactly once and stays in
// registers between the reduction and the store.

#define ETA 0.01f

__global__ __launch_bounds__(256) void internal_opt_kernel(
    const float* __restrict__ W,
    const float* __restrict__ x,
    const float* __restrict__ gL,
    float* __restrict__ out)
{
    const int row = blockIdx.x;            // 0 .. B*D-1  (b = row>>10, i = row&1023)
    const int b   = row >> 10;
    const int t   = threadIdx.x;           // 0..255; thread covers cols 4t..4t+3

    const long long woff = (long long)row * 1024 + (t << 2);
    const float4 w4 = *(const float4*)(W + woff);
    const float4 x4 = *(const float4*)(x + (long long)(b << 10) + (t << 2));

    // partial dot product for (W x)_i
    float p = w4.x * x4.x + w4.y * x4.y + w4.z * x4.z + w4.w * x4.w;

    // wave64 shuffle reduction
    #pragma unroll
    for (int off = 32; off > 0; off >>= 1)
        p += __shfl_down(p, off, 64);

    __shared__ float wave_sum[4];
    __shared__ float s_bcast;
    const int wave = t >> 6;
    if ((t & 63) == 0) wave_sum[wave] = p;
    __syncthreads();
    if (t == 0) {
        const float Wx = wave_sum[0] + wave_sum[1] + wave_sum[2] + wave_sum[3];
        s_bcast = Wx + ETA * gL[row];
    }
    __syncthreads();
    const float s = s_bcast;

    float4 o4;
    o4.x = w4.x - s * x4.x;
    o4.y = w4.y - s * x4.y;
    o4.z = w4.z - s * x4.z;
    o4.w = w4.w - s * x4.w;
    *(float4*)(out + woff) = o4;
}

extern "C" void kernel_launch(void* const* d_in, const int* in_sizes, int n_in,
                              void* d_out, int out_size, void* d_ws, size_t ws_size,
                              hipStream_t stream)
{
    const float* W  = (const float*)d_in[0];
    const float* x  = (const float*)d_in[1];
    const float* gL = (const float*)d_in[2];
    float* out = (float*)d_out;

    const int B = 64, D = 1024;
    dim3 grid(B * D);   // one block per row
    dim3 block(256);
    internal_opt_kernel<<<grid, block, 0, stream>>>(W, x, gL, out);
}